// Round 22
// baseline (62.246 us; speedup 1.0000x reference)
//
#include <hip/hip_runtime.h>
#include <hip/hip_bf16.h>
#include <math.h>

#define T_STEPS 64
#define BATCH   256
#define NX      512
#define NH      512

typedef short bf16x8 __attribute__((ext_vector_type(8)));
typedef float f32x4  __attribute__((ext_vector_type(4)));

__device__ __forceinline__ float dpp_sum64(float v) {
    v += __int_as_float(__builtin_amdgcn_update_dpp(0, __float_as_int(v), 0x111, 0xf, 0xf, true)); // row_shr:1
    v += __int_as_float(__builtin_amdgcn_update_dpp(0, __float_as_int(v), 0x112, 0xf, 0xf, true)); // row_shr:2
    v += __int_as_float(__builtin_amdgcn_update_dpp(0, __float_as_int(v), 0x114, 0xf, 0xf, true)); // row_shr:4
    v += __int_as_float(__builtin_amdgcn_update_dpp(0, __float_as_int(v), 0x118, 0xf, 0xf, true)); // row_shr:8
    v += __int_as_float(__builtin_amdgcn_update_dpp(0, __float_as_int(v), 0x142, 0xf, 0xf, true)); // row_bcast:15
    v += __int_as_float(__builtin_amdgcn_update_dpp(0, __float_as_int(v), 0x143, 0xf, 0xf, true)); // row_bcast:31
    return v;
}

// Sum of lanes 0..7 (within each 16-lane DPP row) lands in lane 7 (mod 16).
__device__ __forceinline__ float dpp_sum8(float v) {
    v += __int_as_float(__builtin_amdgcn_update_dpp(0, __float_as_int(v), 0x111, 0xf, 0xf, true)); // row_shr:1
    v += __int_as_float(__builtin_amdgcn_update_dpp(0, __float_as_int(v), 0x112, 0xf, 0xf, true)); // row_shr:2
    v += __int_as_float(__builtin_amdgcn_update_dpp(0, __float_as_int(v), 0x114, 0xf, 0xf, true)); // row_shr:4
    return v;
}

__device__ __forceinline__ float readlane7(float v) {
    return __int_as_float(__builtin_amdgcn_readlane(__float_as_int(v), 7));
}

__device__ __forceinline__ __hip_bfloat162 cvt2(float a, float b) {
    return __float22bfloat162_rn(make_float2(a, b));
}

// ---------------------------------------------------------------------------
// Prep kernel: W1 f32 -> fragment-ordered bf16 (verified r16-21)
// ---------------------------------------------------------------------------
__global__ __launch_bounds__(256) void w1_prep_kernel(
    const float* __restrict__ w1, unsigned short* __restrict__ w1f)
{
    int tid = blockIdx.x * 256 + threadIdx.x;   // 0..32767
    int row = tid >> 6;
    int oct = tid & 63;
    const float* s = &w1[(size_t)row * 512 + oct * 8];
    float4 v0 = *(const float4*)s;
    float4 v1 = *(const float4*)(s + 4);
    union { __hip_bfloat162 q[4]; int4 pk; } u;
    u.q[0] = cvt2(v0.x, v0.y); u.q[1] = cvt2(v0.z, v0.w);
    u.q[2] = cvt2(v1.x, v1.y); u.q[3] = cvt2(v1.z, v1.w);
    int g = ((oct >> 2) * 32 + (row >> 4)) * 64 + (row & 15) + 16 * (oct & 3);
    *(int4*)&w1f[(size_t)g * 8] = u.pk;
}

// ---------------------------------------------------------------------------
// FUSED kernel — r21 structure (verified 59.92 us) with TWO step-loop
// LDS-issue reductions (all else byte-identical):
//   (1) phase-D chain-coefficient reads vectorized: avg ~7.5 scalar b32 ->
//       ~2.4 b128 per thread per step (indices compile-time static).
//   (2) red layout interleaved ([2w]=p0,[2w+1]=p1) -> phase A reads ONE
//       b64 instead of two b32 8-floats apart.
// ---------------------------------------------------------------------------
__global__ __launch_bounds__(512, 1) void fused_kernel(
    const float* __restrict__ x,    // [T][B][NX]
    const unsigned short* __restrict__ w1f,  // fragment-ordered bf16 W1
    const float* __restrict__ b1,   // [NH]
    const float* __restrict__ w2,   // [NH][2]
    const float* __restrict__ b2,   // [2]
    const float* __restrict__ w21,  // [NH][2]
    const float* __restrict__ lamp,
    const float* __restrict__ etap,
    float* __restrict__ outH,       // [T][B][NH]
    float* __restrict__ outY)       // [T][B][2]
{
    const int b    = blockIdx.x;
    const int h    = threadIdx.x;
    const int lane = h & 63;
    const int wv   = h >> 6;

    __shared__ float Hs[64][512];   // 128 KB; rows<t hold h, rows>=t hold P;
                                    // first 64 KB doubles as xs during setup
    __shared__ float Gl[64][66];
    __shared__ float C[16][64];
    __shared__ float lam_pow[64];
    __shared__ float red[2][16];    // [par][2w]=p0 partial, [2w+1]=p1 partial

    unsigned short* xs = (unsigned short*)&Hs[0][0];

    const float eta = etap[0];
    const float lam = fminf(lamp[0], 1.0f);
    const float2 w21v = *(const float2*)&w21[2 * h];
    const float2 w2v  = *(const float2*)&w2[2 * h];
    const float b20 = b2[0], b21 = b2[1];
    float* oHb = outH + (size_t)b * NH + h;

    // ---- phase 1: coalesced X staging -----------------------------------
    if (h < 64)
        lam_pow[h] = (h == 0) ? 1.0f : exp2f((float)h * log2f(lam));
#pragma unroll
    for (int i = 0; i < 8; ++i) {
        int r = wv + i * 8;
        int o = lane;
        const float* src = &x[((size_t)r * BATCH + b) * NX + o * 8];
        float4 v0 = *(const float4*)src;
        float4 v1 = *(const float4*)(src + 4);
        union { __hip_bfloat162 q[4]; int4 pk; } u;
        u.q[0] = cvt2(v0.x, v0.y); u.q[1] = cvt2(v0.z, v0.w);
        u.q[2] = cvt2(v1.x, v1.y); u.q[3] = cvt2(v1.z, v1.w);
        int g = ((o >> 2) * 4 + (r >> 4)) * 64 + (r & 15) + 16 * (o & 3);
        *(int4*)&xs[g * 8] = u.pk;
    }
    __syncthreads();   // xs + lam_pow visible

    // ---- phase 3 prefetch (misses fly under Gram) -----------------------
    bf16x8 bfp[2][4];
#pragma unroll
    for (int nf = 0; nf < 4; ++nf)
        bfp[0][nf] = *(const bf16x8*)&w1f[(size_t)((wv * 4 + nf) * 64 + lane) * 8];

    // ---- phase 2: Gram -> Gl (2 tiles per wave) -------------------------
    {
        const int mt_g = wv >> 1;
#pragma unroll
        for (int j = 0; j < 2; ++j) {
            const int nt_g = (wv & 1) * 2 + j;
            f32x4 gacc = {};
#pragma unroll
            for (int ks = 0; ks < 16; ++ks) {
                bf16x8 afr = *(const bf16x8*)&xs[((ks * 4 + mt_g) * 64 + lane) * 8];
                bf16x8 bfr = *(const bf16x8*)&xs[((ks * 4 + nt_g) * 64 + lane) * 8];
                gacc = __builtin_amdgcn_mfma_f32_16x16x32_bf16(afr, bfr, gacc, 0, 0, 0);
            }
#pragma unroll
            for (int r = 0; r < 4; ++r)
                Gl[mt_g * 16 + ((lane >> 4) << 2) + r][nt_g * 16 + (lane & 15)] = gacc[r];
        }
    }

    // ---- phase 3: P-GEMM (A from xs, B direct bf16 from w1f) ------------
    {
        f32x4 pacc[4][4] = {};
#pragma unroll
        for (int ks = 0; ks < 16; ++ks) {
            if (ks < 15) {
#pragma unroll
                for (int nf = 0; nf < 4; ++nf)
                    bfp[(ks + 1) & 1][nf] = *(const bf16x8*)
                        &w1f[(size_t)(((ks + 1) * 32 + wv * 4 + nf) * 64 + lane) * 8];
            }
            bf16x8 afr[4];
#pragma unroll
            for (int mt = 0; mt < 4; ++mt)
                afr[mt] = *(const bf16x8*)&xs[((ks * 4 + mt) * 64 + lane) * 8];
#pragma unroll
            for (int mt = 0; mt < 4; ++mt)
#pragma unroll
                for (int nf = 0; nf < 4; ++nf)
                    pacc[mt][nf] = __builtin_amdgcn_mfma_f32_16x16x32_bf16(
                        afr[mt], bfp[ks & 1][nf], pacc[mt][nf], 0, 0, 0);
        }

        __syncthreads();   // ALL xs reads complete before P overwrites rows 0..31

        // epilogue: +b1, write P into Hs (LDS) — static indices only
        float bc[4];
#pragma unroll
        for (int nf = 0; nf < 4; ++nf)
            bc[nf] = b1[wv * 64 + nf * 16 + (lane & 15)];
#pragma unroll
        for (int mt = 0; mt < 4; ++mt) {
#pragma unroll
            for (int nf = 0; nf < 4; ++nf) {
#pragma unroll
                for (int r = 0; r < 4; ++r) {
                    int t = mt * 16 + ((lane >> 4) << 2) + r;
                    int n = wv * 64 + nf * 16 + (lane & 15);
                    Hs[t][n] = pacc[mt][nf][r] + bc[nf];
                }
            }
        }
    }
    __syncthreads();   // P (in Hs) visible block-wide

    // ---- phase 4: scan --------------------------------------------------
#pragma unroll 1
    for (int c = 0; c < 4; ++c) {
        const int t0 = c * 16;

#pragma unroll
        for (int e = h; e < 1024; e += 512) {
            int tt = e >> 6, s = e & 63;
            int t  = t0 + tt;
            float cv = 0.f;
            if (s < t) cv = eta * lam_pow[t - 1 - s] * Gl[t][s];
            C[tt][s] = cv;
        }

        // P rows t0..t0+15 still untouched; read into registers now.
        float pvreg[16];
#pragma unroll
        for (int tt = 0; tt < 16; ++tt)
            pvreg[tt] = Hs[t0 + tt][h];

        __syncthreads();   // C visible; orders prev chunk's last red write

        float macc[16] = {};
        for (int s4 = 0; s4 < t0; s4 += 4) {
            float hsv0 = Hs[s4 + 0][h];
            float hsv1 = Hs[s4 + 1][h];
            float hsv2 = Hs[s4 + 2][h];
            float hsv3 = Hs[s4 + 3][h];
#pragma unroll
            for (int tt = 0; tt < 16; ++tt) {
                float4 cf = *(const float4*)&C[tt][s4];
                macc[tt] = fmaf(cf.x, hsv0, macc[tt]);
                macc[tt] = fmaf(cf.y, hsv1, macc[tt]);
                macc[tt] = fmaf(cf.z, hsv2, macc[tt]);
                macc[tt] = fmaf(cf.w, hsv3, macc[tt]);
            }
        }

        float hcur[16];
        float partial = pvreg[0] + macc[0];
#pragma unroll
        for (int tt = 0; tt < 16; ++tt) {
            const int t = t0 + tt;

            // phase A: a2_t from prev step's per-wave partials.
            // ONE b64 broadcast read + 2x3 DPP adds + readlane -> SGPR.
            float a2x, a2y;
            if (t == 0) {
                a2x = 0.f; a2y = 0.f;
            } else {
                const int pr = (t - 1) & 1;
                float2 rp = *(const float2*)&red[pr][(lane & 7) * 2];
                float s0 = b20 + readlane7(dpp_sum8(rp.x));
                float s1 = b21 + readlane7(dpp_sum8(rp.y));
                a2x = s0; a2y = s1;
                if (h == 0) {
                    outY[((size_t)(t - 1) * BATCH + b) * 2 + 0] = 1.0f / (1.0f + __expf(-s0));
                    outY[((size_t)(t - 1) * BATCH + b) * 2 + 1] = 1.0f / (1.0f + __expf(-s1));
                }
            }

            float a1 = partial + w21v.x * a2x + w21v.y * a2y;
            float hv = 1.0f / (1.0f + __expf(-a1));
            hcur[tt] = hv;
            Hs[t][h] = hv;          // row t: P already consumed (pvreg)
            oHb[(size_t)t * (BATCH * NH)] = hv;

            float p0 = dpp_sum64(hv * w2v.x);
            float p1 = dpp_sum64(hv * w2v.y);
            if ((h & 63) == 63) {
                red[t & 1][wv * 2]     = p0;
                red[t & 1][wv * 2 + 1] = p1;
            }

            // phase D (off the a2 chain): next step's partial, b128 C reads
            if (tt < 15) {
                partial = pvreg[tt + 1] + macc[tt + 1];
#pragma unroll
                for (int q = 0; q <= (tt >> 2); ++q) {
                    float4 cf = *(const float4*)&C[tt + 1][t0 + 4 * q];
                    partial = fmaf(cf.x, hcur[4 * q + 0], partial);
                    if (tt + 1 - 4 * q > 1) partial = fmaf(cf.y, hcur[4 * q + 1], partial);
                    if (tt + 1 - 4 * q > 2) partial = fmaf(cf.z, hcur[4 * q + 2], partial);
                    if (tt + 1 - 4 * q > 3) partial = fmaf(cf.w, hcur[4 * q + 3], partial);
                }
            }

            __syncthreads();
        }
    }

    // ---- tail: outY[63] from the final partials -------------------------
    {
        const int pr = 63 & 1;
        float2 rp = *(const float2*)&red[pr][(lane & 7) * 2];
        float s0 = b20 + readlane7(dpp_sum8(rp.x));
        float s1 = b21 + readlane7(dpp_sum8(rp.y));
        if (h == 0) {
            outY[((size_t)63 * BATCH + b) * 2 + 0] = 1.0f / (1.0f + __expf(-s0));
            outY[((size_t)63 * BATCH + b) * 2 + 1] = 1.0f / (1.0f + __expf(-s1));
        }
    }
}

// ---------------------------------------------------------------------------
extern "C" void kernel_launch(void* const* d_in, const int* in_sizes, int n_in,
                              void* d_out, int out_size, void* d_ws, size_t ws_size,
                              hipStream_t stream) {
    const float* x   = (const float*)d_in[0];
    const float* w1  = (const float*)d_in[1];
    const float* b1  = (const float*)d_in[2];
    const float* w2  = (const float*)d_in[3];
    const float* b2  = (const float*)d_in[4];
    const float* w21 = (const float*)d_in[5];
    const float* lam = (const float*)d_in[6];
    const float* eta = (const float*)d_in[7];

    float* outH = (float*)d_out;                       // [64*256*512]
    float* outY = outH + (size_t)T_STEPS * BATCH * NH; // [64*256*2]
    unsigned short* w1f = (unsigned short*)d_ws;       // 512 KB bf16 W1 frags

    w1_prep_kernel<<<128, 256, 0, stream>>>(w1, w1f);
    fused_kernel<<<256, 512, 0, stream>>>(x, w1f, b1, w2, b2, w21, lam, eta, outH, outY);
}

// Round 23
// 59.832 us; speedup vs baseline: 1.0403x; 1.0403x over previous
//
#include <hip/hip_runtime.h>
#include <hip/hip_bf16.h>
#include <math.h>

#define T_STEPS 64
#define BATCH   256
#define NX      512
#define NH      512

typedef short bf16x8 __attribute__((ext_vector_type(8)));
typedef float f32x4  __attribute__((ext_vector_type(4)));

__device__ __forceinline__ float dpp_sum64(float v) {
    v += __int_as_float(__builtin_amdgcn_update_dpp(0, __float_as_int(v), 0x111, 0xf, 0xf, true)); // row_shr:1
    v += __int_as_float(__builtin_amdgcn_update_dpp(0, __float_as_int(v), 0x112, 0xf, 0xf, true)); // row_shr:2
    v += __int_as_float(__builtin_amdgcn_update_dpp(0, __float_as_int(v), 0x114, 0xf, 0xf, true)); // row_shr:4
    v += __int_as_float(__builtin_amdgcn_update_dpp(0, __float_as_int(v), 0x118, 0xf, 0xf, true)); // row_shr:8
    v += __int_as_float(__builtin_amdgcn_update_dpp(0, __float_as_int(v), 0x142, 0xf, 0xf, true)); // row_bcast:15
    v += __int_as_float(__builtin_amdgcn_update_dpp(0, __float_as_int(v), 0x143, 0xf, 0xf, true)); // row_bcast:31
    return v;
}

// Sum of lanes 0..7 (within each 16-lane DPP row) lands in lane 7 (mod 16).
// row_shr moves values UP-lane only -> lane 7 receives only from lanes 0..6.
__device__ __forceinline__ float dpp_sum8(float v) {
    v += __int_as_float(__builtin_amdgcn_update_dpp(0, __float_as_int(v), 0x111, 0xf, 0xf, true)); // row_shr:1
    v += __int_as_float(__builtin_amdgcn_update_dpp(0, __float_as_int(v), 0x112, 0xf, 0xf, true)); // row_shr:2
    v += __int_as_float(__builtin_amdgcn_update_dpp(0, __float_as_int(v), 0x114, 0xf, 0xf, true)); // row_shr:4
    return v;
}

__device__ __forceinline__ float readlane7(float v) {
    return __int_as_float(__builtin_amdgcn_readlane(__float_as_int(v), 7));
}

__device__ __forceinline__ __hip_bfloat162 cvt2(float a, float b) {
    return __float22bfloat162_rn(make_float2(a, b));
}

// ---------------------------------------------------------------------------
// Prep kernel: W1 f32 -> fragment-ordered bf16 (verified r16-22)
// ---------------------------------------------------------------------------
__global__ __launch_bounds__(256) void w1_prep_kernel(
    const float* __restrict__ w1, unsigned short* __restrict__ w1f)
{
    int tid = blockIdx.x * 256 + threadIdx.x;   // 0..32767
    int row = tid >> 6;
    int oct = tid & 63;
    const float* s = &w1[(size_t)row * 512 + oct * 8];
    float4 v0 = *(const float4*)s;
    float4 v1 = *(const float4*)(s + 4);
    union { __hip_bfloat162 q[4]; int4 pk; } u;
    u.q[0] = cvt2(v0.x, v0.y); u.q[1] = cvt2(v0.z, v0.w);
    u.q[2] = cvt2(v1.x, v1.y); u.q[3] = cvt2(v1.z, v1.w);
    int g = ((oct >> 2) * 32 + (row >> 4)) * 64 + (row & 15) + 16 * (oct & 3);
    *(int4*)&w1f[(size_t)g * 8] = u.pk;
}

// ---------------------------------------------------------------------------
// FUSED kernel — EXACT round-21 version (best verified: 59.92 us).
//   r22's phase-D b128 + red-interleave experiment regressed (+2.3 us,
//   falsifier fired: uniform LDS broadcasts cost ~1-2 cy, not 4-6) ->
//   reverted. Twelve scan step-loop variants have landed 47.5-51 us:
//   the loop is bound by the 8-wave barrier cadence + ~450 cy serial a2
//   chain, not any counter-visible resource (HBM 11%, MFMA 6%, VALU 37%,
//   conflicts ~0.1 us). This is the final state.
//   Phase 1: X_b -> xs bf16 frags (coalesced).
//   Phase 2: Gram -> Gl via MFMA.
//   Phase 3: P-GEMM (B direct bf16 from w1f, 2-deep parity prefetch);
//            epilogue writes P+b1 into Hs (LDS) — no HBM round-trip.
//   Phase 4: scan — r12 skeleton + r21's cheap phase-A reduce
//            (8 partials in red, 1 b32 + dpp_sum8 + readlane -> SGPR).
// ---------------------------------------------------------------------------
__global__ __launch_bounds__(512, 1) void fused_kernel(
    const float* __restrict__ x,    // [T][B][NX]
    const unsigned short* __restrict__ w1f,  // fragment-ordered bf16 W1
    const float* __restrict__ b1,   // [NH]
    const float* __restrict__ w2,   // [NH][2]
    const float* __restrict__ b2,   // [2]
    const float* __restrict__ w21,  // [NH][2]
    const float* __restrict__ lamp,
    const float* __restrict__ etap,
    float* __restrict__ outH,       // [T][B][NH]
    float* __restrict__ outY)       // [T][B][2]
{
    const int b    = blockIdx.x;
    const int h    = threadIdx.x;
    const int lane = h & 63;
    const int wv   = h >> 6;

    __shared__ float Hs[64][512];   // 128 KB; rows<t hold h, rows>=t hold P;
                                    // first 64 KB doubles as xs during setup
    __shared__ float Gl[64][66];
    __shared__ float C[16][64];
    __shared__ float lam_pow[64];
    __shared__ float red[2][16];    // [par][0..7]=p0 partials, [8..15]=p1

    unsigned short* xs = (unsigned short*)&Hs[0][0];

    const float eta = etap[0];
    const float lam = fminf(lamp[0], 1.0f);
    const float2 w21v = *(const float2*)&w21[2 * h];
    const float2 w2v  = *(const float2*)&w2[2 * h];
    const float b20 = b2[0], b21 = b2[1];
    float* oHb = outH + (size_t)b * NH + h;

    // ---- phase 1: coalesced X staging -----------------------------------
    if (h < 64)
        lam_pow[h] = (h == 0) ? 1.0f : exp2f((float)h * log2f(lam));
#pragma unroll
    for (int i = 0; i < 8; ++i) {
        int r = wv + i * 8;
        int o = lane;
        const float* src = &x[((size_t)r * BATCH + b) * NX + o * 8];
        float4 v0 = *(const float4*)src;
        float4 v1 = *(const float4*)(src + 4);
        union { __hip_bfloat162 q[4]; int4 pk; } u;
        u.q[0] = cvt2(v0.x, v0.y); u.q[1] = cvt2(v0.z, v0.w);
        u.q[2] = cvt2(v1.x, v1.y); u.q[3] = cvt2(v1.z, v1.w);
        int g = ((o >> 2) * 4 + (r >> 4)) * 64 + (r & 15) + 16 * (o & 3);
        *(int4*)&xs[g * 8] = u.pk;
    }
    __syncthreads();   // xs + lam_pow visible

    // ---- phase 3 prefetch (misses fly under Gram) -----------------------
    bf16x8 bfp[2][4];
#pragma unroll
    for (int nf = 0; nf < 4; ++nf)
        bfp[0][nf] = *(const bf16x8*)&w1f[(size_t)((wv * 4 + nf) * 64 + lane) * 8];

    // ---- phase 2: Gram -> Gl (2 tiles per wave) -------------------------
    {
        const int mt_g = wv >> 1;
#pragma unroll
        for (int j = 0; j < 2; ++j) {
            const int nt_g = (wv & 1) * 2 + j;
            f32x4 gacc = {};
#pragma unroll
            for (int ks = 0; ks < 16; ++ks) {
                bf16x8 afr = *(const bf16x8*)&xs[((ks * 4 + mt_g) * 64 + lane) * 8];
                bf16x8 bfr = *(const bf16x8*)&xs[((ks * 4 + nt_g) * 64 + lane) * 8];
                gacc = __builtin_amdgcn_mfma_f32_16x16x32_bf16(afr, bfr, gacc, 0, 0, 0);
            }
#pragma unroll
            for (int r = 0; r < 4; ++r)
                Gl[mt_g * 16 + ((lane >> 4) << 2) + r][nt_g * 16 + (lane & 15)] = gacc[r];
        }
    }

    // ---- phase 3: P-GEMM (A from xs, B direct bf16 from w1f) ------------
    {
        f32x4 pacc[4][4] = {};
#pragma unroll
        for (int ks = 0; ks < 16; ++ks) {
            if (ks < 15) {
#pragma unroll
                for (int nf = 0; nf < 4; ++nf)
                    bfp[(ks + 1) & 1][nf] = *(const bf16x8*)
                        &w1f[(size_t)(((ks + 1) * 32 + wv * 4 + nf) * 64 + lane) * 8];
            }
            bf16x8 afr[4];
#pragma unroll
            for (int mt = 0; mt < 4; ++mt)
                afr[mt] = *(const bf16x8*)&xs[((ks * 4 + mt) * 64 + lane) * 8];
#pragma unroll
            for (int mt = 0; mt < 4; ++mt)
#pragma unroll
                for (int nf = 0; nf < 4; ++nf)
                    pacc[mt][nf] = __builtin_amdgcn_mfma_f32_16x16x32_bf16(
                        afr[mt], bfp[ks & 1][nf], pacc[mt][nf], 0, 0, 0);
        }

        __syncthreads();   // ALL xs reads complete before P overwrites rows 0..31

        // epilogue: +b1, write P into Hs (LDS) — static indices only
        float bc[4];
#pragma unroll
        for (int nf = 0; nf < 4; ++nf)
            bc[nf] = b1[wv * 64 + nf * 16 + (lane & 15)];
#pragma unroll
        for (int mt = 0; mt < 4; ++mt) {
#pragma unroll
            for (int nf = 0; nf < 4; ++nf) {
#pragma unroll
                for (int r = 0; r < 4; ++r) {
                    int t = mt * 16 + ((lane >> 4) << 2) + r;
                    int n = wv * 64 + nf * 16 + (lane & 15);
                    Hs[t][n] = pacc[mt][nf][r] + bc[nf];
                }
            }
        }
    }
    __syncthreads();   // P (in Hs) visible block-wide

    // ---- phase 4: scan --------------------------------------------------
#pragma unroll 1
    for (int c = 0; c < 4; ++c) {
        const int t0 = c * 16;

#pragma unroll
        for (int e = h; e < 1024; e += 512) {
            int tt = e >> 6, s = e & 63;
            int t  = t0 + tt;
            float cv = 0.f;
            if (s < t) cv = eta * lam_pow[t - 1 - s] * Gl[t][s];
            C[tt][s] = cv;
        }

        // P rows t0..t0+15 still untouched; read into registers now.
        float pvreg[16];
#pragma unroll
        for (int tt = 0; tt < 16; ++tt)
            pvreg[tt] = Hs[t0 + tt][h];

        __syncthreads();   // C visible; orders prev chunk's last red write

        float macc[16] = {};
        for (int s4 = 0; s4 < t0; s4 += 4) {
            float hsv0 = Hs[s4 + 0][h];
            float hsv1 = Hs[s4 + 1][h];
            float hsv2 = Hs[s4 + 2][h];
            float hsv3 = Hs[s4 + 3][h];
#pragma unroll
            for (int tt = 0; tt < 16; ++tt) {
                float4 cf = *(const float4*)&C[tt][s4];
                macc[tt] = fmaf(cf.x, hsv0, macc[tt]);
                macc[tt] = fmaf(cf.y, hsv1, macc[tt]);
                macc[tt] = fmaf(cf.z, hsv2, macc[tt]);
                macc[tt] = fmaf(cf.w, hsv3, macc[tt]);
            }
        }

        float hcur[16];
        float partial = pvreg[0] + macc[0];
#pragma unroll
        for (int tt = 0; tt < 16; ++tt) {
            const int t = t0 + tt;

            // phase A: a2_t from prev step's per-wave partials.
            // 2 x b32 broadcast reads + 3 DPP adds + readlane -> SGPR.
            float a2x, a2y;
            if (t == 0) {
                a2x = 0.f; a2y = 0.f;
            } else {
                const int pr = (t - 1) & 1;
                float r0 = red[pr][lane & 7];       // p0 partial of wave (lane&7)
                float r1 = red[pr][8 + (lane & 7)]; // p1 partial
                float s0 = b20 + readlane7(dpp_sum8(r0));
                float s1 = b21 + readlane7(dpp_sum8(r1));
                a2x = s0; a2y = s1;
                if (h == 0) {
                    outY[((size_t)(t - 1) * BATCH + b) * 2 + 0] = 1.0f / (1.0f + __expf(-s0));
                    outY[((size_t)(t - 1) * BATCH + b) * 2 + 1] = 1.0f / (1.0f + __expf(-s1));
                }
            }

            float a1 = partial + w21v.x * a2x + w21v.y * a2y;
            float hv = 1.0f / (1.0f + __expf(-a1));
            hcur[tt] = hv;
            Hs[t][h] = hv;          // row t: P already consumed (pvreg)
            oHb[(size_t)t * (BATCH * NH)] = hv;

            float p0 = dpp_sum64(hv * w2v.x);
            float p1 = dpp_sum64(hv * w2v.y);
            if ((h & 63) == 63) {
                red[t & 1][wv]     = p0;
                red[t & 1][8 + wv] = p1;
            }

            if (tt < 15) {
                partial = pvreg[tt + 1] + macc[tt + 1];
#pragma unroll
                for (int j = 0; j <= tt; ++j)
                    partial = fmaf(C[tt + 1][t0 + j], hcur[j], partial);
            }

            __syncthreads();
        }
    }

    // ---- tail: outY[63] from the final partials -------------------------
    {
        const int pr = 63 & 1;
        float r0 = red[pr][lane & 7];
        float r1 = red[pr][8 + (lane & 7)];
        float s0 = b20 + readlane7(dpp_sum8(r0));
        float s1 = b21 + readlane7(dpp_sum8(r1));
        if (h == 0) {
            outY[((size_t)63 * BATCH + b) * 2 + 0] = 1.0f / (1.0f + __expf(-s0));
            outY[((size_t)63 * BATCH + b) * 2 + 1] = 1.0f / (1.0f + __expf(-s1));
        }
    }
}

// ---------------------------------------------------------------------------
extern "C" void kernel_launch(void* const* d_in, const int* in_sizes, int n_in,
                              void* d_out, int out_size, void* d_ws, size_t ws_size,
                              hipStream_t stream) {
    const float* x   = (const float*)d_in[0];
    const float* w1  = (const float*)d_in[1];
    const float* b1  = (const float*)d_in[2];
    const float* w2  = (const float*)d_in[3];
    const float* b2  = (const float*)d_in[4];
    const float* w21 = (const float*)d_in[5];
    const float* lam = (const float*)d_in[6];
    const float* eta = (const float*)d_in[7];

    float* outH = (float*)d_out;                       // [64*256*512]
    float* outY = outH + (size_t)T_STEPS * BATCH * NH; // [64*256*2]
    unsigned short* w1f = (unsigned short*)d_ws;       // 512 KB bf16 W1 frags

    w1_prep_kernel<<<128, 256, 0, stream>>>(w1, w1f);
    fused_kernel<<<256, 512, 0, stream>>>(x, w1f, b1, w2, b2, w21, lam, eta, outH, outY);
}